// Round 2
// baseline (2845.724 us; speedup 1.0000x reference)
//
#include <hip/hip_runtime.h>

// Problem constants
#define NPAR   8192      // parents
#define NCH    65536     // children = NPAR*8
#define RES    32
#define EPS    1e-5f

// ---------------------------------------------------------------------------
// init: grid32 = -1 (32768 entries = 128 blocks * 256), stats[128] = 0
__global__ void init_kernel(int* __restrict__ grid32, float* __restrict__ stats) {
    int idx = blockIdx.x * 256 + threadIdx.x;
    grid32[idx] = -1;
    if (idx < 128) stats[idx] = 0.0f;  // gn1 sum[32], gn1 sq[32], gn2 sum[32], gn2 sq[32]
}

// scatter parent indices into 32^3 grid
__global__ void scatter_kernel(const int* __restrict__ coords, int* __restrict__ grid32) {
    int p = blockIdx.x * 256 + threadIdx.x;
    if (p >= NPAR) return;
    int x = coords[p * 3 + 0], y = coords[p * 3 + 1], z = coords[p * 3 + 2];
    grid32[(x << 10) + (y << 5) + z] = p;
}

// ---------------------------------------------------------------------------
// Fold 27-tap fine-grid weights into 64 parent-level matrices for CONV1 ONLY.
// Valid because conv1's input is repeat(h,8): all children of a parent share
// one feature row. (NOT valid for conv2 — its input rows are distinct.)
// Wc1[o][s][ci][c]: o = child bits (ox<<2|oy<<1|oz), s = slot bits,
// parent delta e_a = o_a + s_a - 1; fine taps d summed per (o,s):
// (o=0,s=0):{-1}  (o=0,s=1):{0,1}  (o=1,s=0):{-1,0}  (o=1,s=1):{1}
__device__ __forceinline__ void axis_dlist(int o, int s, int* d, int& n) {
    if (o == 0) { if (s == 0) { d[0] = -1; n = 1; } else { d[0] = 0; d[1] = 1; n = 2; } }
    else        { if (s == 0) { d[0] = -1; d[1] = 0; n = 2; } else { d[0] = 1; n = 1; } }
}

__global__ void fold_kernel(const float* __restrict__ W1, float* __restrict__ Wc1) {
    int idx = blockIdx.x * 256 + threadIdx.x;   // 64 * 16384 total
    int os = idx >> 14;        // o*8 + s
    int mat = idx & 16383;     // ci*128 + c
    int o = os >> 3, s = os & 7;
    int d0[2], d1[2], d2[2], n0, n1, n2;
    axis_dlist((o >> 2) & 1, (s >> 2) & 1, d0, n0);
    axis_dlist((o >> 1) & 1, (s >> 1) & 1, d1, n1);
    axis_dlist(o & 1,        s & 1,        d2, n2);
    float acc = 0.0f;
    for (int a = 0; a < n0; ++a)
        for (int b = 0; b < n1; ++b)
            for (int cc = 0; cc < n2; ++cc) {
                int k = (d0[a] + 1) * 9 + (d1[b] + 1) * 3 + (d2[cc] + 1);
                acc += W1[k * 16384 + mat];
            }
    Wc1[idx] = acc;
}

// ---------------------------------------------------------------------------
// GroupNorm stats over ALL rows (axis 0 and 2). C/G = 4 -> one float4 = one group.
__global__ void gn_stats_kernel(const float* __restrict__ x, float* __restrict__ sum,
                                float* __restrict__ sq, int nrows) {
    __shared__ float s_sum[32], s_sq[32];
    int t = threadIdx.x;
    if (t < 32) { s_sum[t] = 0.0f; s_sq[t] = 0.0f; }
    __syncthreads();
    const float4* x4 = (const float4*)x;
    int total = nrows * 32;
    int idx0 = blockIdx.x * blockDim.x + t;
    int g = idx0 & 31;  // stride multiple of 32 -> group fixed per thread
    float ls = 0.0f, lq = 0.0f;
    for (int idx = idx0; idx < total; idx += gridDim.x * blockDim.x) {
        float4 v = x4[idx];
        ls += v.x + v.y + v.z + v.w;
        lq += v.x * v.x + v.y * v.y + v.z * v.z + v.w * v.w;
    }
    atomicAdd(&s_sum[g], ls);
    atomicAdd(&s_sq[g], lq);
    __syncthreads();
    if (t < 32) { atomicAdd(&sum[t], s_sum[t]); atomicAdd(&sq[t], s_sq[t]); }
}

// groupnorm + silu elementwise
__global__ void gn_apply_kernel(const float* __restrict__ x, const float* __restrict__ sum,
                                const float* __restrict__ sq, const float* __restrict__ gamma,
                                const float* __restrict__ beta, float* __restrict__ y, int nrows) {
    const float4* x4 = (const float4*)x;
    float4* y4 = (float4*)y;
    const float4* g4 = (const float4*)gamma;
    const float4* b4 = (const float4*)beta;
    float cnt = (float)nrows * 4.0f;
    int total = nrows * 32;
    for (int idx = blockIdx.x * blockDim.x + threadIdx.x; idx < total;
         idx += gridDim.x * blockDim.x) {
        int c4 = idx & 31;
        float mean = sum[c4] / cnt;
        float var = sq[c4] / cnt - mean * mean;
        float rstd = rsqrtf(var + EPS);
        float4 v = x4[idx];
        float4 gm = g4[c4];
        float4 bt = b4[c4];
        float a[4] = {v.x, v.y, v.z, v.w};
        float gg[4] = {gm.x, gm.y, gm.z, gm.w};
        float bb[4] = {bt.x, bt.y, bt.z, bt.w};
        float o[4];
#pragma unroll
        for (int i = 0; i < 4; ++i) {
            float tv = (a[i] - mean) * rstd * gg[i] + bb[i];
            o[i] = tv / (1.0f + __expf(-tv));
        }
        y4[idx] = make_float4(o[0], o[1], o[2], o[3]);
    }
}

// ---------------------------------------------------------------------------
// CONV1 (folded): block = 16 parents, 256 threads.
// thread(tx=t&31 -> 4 cols, ty=t>>5 -> parents ty*2, ty*2+1), acc[2][8] float4.
// Loop e over 27 parent-neighbor offsets: stage 16 neighbor rows of h0 in LDS,
// then for each valid child o (s_a = e_a + 1 - o_a in {0,1}) accumulate
// inrow @ Wc1[o][s].
__global__ void __launch_bounds__(256) conv1_kernel(
    const float* __restrict__ h0, const float* __restrict__ Wc1,
    const float* __restrict__ b1, const int* __restrict__ grid32,
    const int* __restrict__ coords, float* __restrict__ out) {
    __shared__ int   pc[16][3];
    __shared__ int   rowsrc[16];
    __shared__ float inbuf[16 * 128];   // 8 KB
    int t = threadIdx.x;
    int P0 = blockIdx.x * 16;
    if (t < 48) pc[t / 3][t % 3] = coords[(P0 + t / 3) * 3 + t % 3];
    int tx = t & 31, ty = t >> 5;
    float4 acc[2][8];
#pragma unroll
    for (int p = 0; p < 2; ++p)
#pragma unroll
        for (int o = 0; o < 8; ++o) acc[p][o] = make_float4(0.f, 0.f, 0.f, 0.f);
    __syncthreads();

#pragma unroll 1
    for (int e = 0; e < 27; ++e) {
        int ex = e / 9 - 1, ey = (e / 3) % 3 - 1, ez = e % 3 - 1;
        __syncthreads();   // previous compute done with inbuf/rowsrc
        if (t < 16) {
            int nx = pc[t][0] + ex, ny = pc[t][1] + ey, nz = pc[t][2] + ez;
            int r = -1;
            if ((unsigned)nx < 32u && (unsigned)ny < 32u && (unsigned)nz < 32u)
                r = grid32[(nx << 10) + (ny << 5) + nz];
            rowsrc[t] = r;
        }
        __syncthreads();
        // gather 16 rows; lane-contiguous LDS writes (no bank conflicts)
#pragma unroll
        for (int j = 0; j < 2; ++j) {
            int row = j * 8 + ty;
            int src = rowsrc[row];
            float4 v = make_float4(0.f, 0.f, 0.f, 0.f);
            if (src >= 0) v = ((const float4*)h0)[src * 32 + tx];
            ((float4*)inbuf)[row * 32 + tx] = v;
        }
        __syncthreads();
#pragma unroll
        for (int o = 0; o < 8; ++o) {
            int s0 = ex + 1 - ((o >> 2) & 1);
            int s1 = ey + 1 - ((o >> 1) & 1);
            int s2 = ez + 1 - (o & 1);
            if ((unsigned)s0 > 1u || (unsigned)s1 > 1u || (unsigned)s2 > 1u) continue;
            const float4* W4 =
                (const float4*)(Wc1 + (((o << 3) + (s0 << 2) + (s1 << 1) + s2) << 14));
#pragma unroll
            for (int p = 0; p < 2; ++p) {
                int pi = ty * 2 + p;
                if (rowsrc[pi] < 0) continue;
                const float4* A4 = (const float4*)(inbuf + pi * 128);
                float4 ac = acc[p][o];
#pragma unroll 4
                for (int ci4 = 0; ci4 < 32; ++ci4) {
                    float4 a4 = A4[ci4];
                    float4 w;
                    w = W4[(ci4 * 4 + 0) * 32 + tx];
                    ac.x = fmaf(a4.x, w.x, ac.x); ac.y = fmaf(a4.x, w.y, ac.y);
                    ac.z = fmaf(a4.x, w.z, ac.z); ac.w = fmaf(a4.x, w.w, ac.w);
                    w = W4[(ci4 * 4 + 1) * 32 + tx];
                    ac.x = fmaf(a4.y, w.x, ac.x); ac.y = fmaf(a4.y, w.y, ac.y);
                    ac.z = fmaf(a4.y, w.z, ac.z); ac.w = fmaf(a4.y, w.w, ac.w);
                    w = W4[(ci4 * 4 + 2) * 32 + tx];
                    ac.x = fmaf(a4.z, w.x, ac.x); ac.y = fmaf(a4.z, w.y, ac.y);
                    ac.z = fmaf(a4.z, w.z, ac.z); ac.w = fmaf(a4.z, w.w, ac.w);
                    w = W4[(ci4 * 4 + 3) * 32 + tx];
                    ac.x = fmaf(a4.w, w.x, ac.x); ac.y = fmaf(a4.w, w.y, ac.y);
                    ac.z = fmaf(a4.w, w.z, ac.z); ac.w = fmaf(a4.w, w.w, ac.w);
                }
                acc[p][o] = ac;
            }
        }
    }
    float4 bias = ((const float4*)b1)[tx];
#pragma unroll
    for (int p = 0; p < 2; ++p)
#pragma unroll
        for (int o = 0; o < 8; ++o) {
            float4 v = acc[p][o];
            v.x += bias.x; v.y += bias.y; v.z += bias.z; v.w += bias.w;
            int R = (P0 + ty * 2 + p) * 8 + o;
            ((float4*)out)[R * 32 + tx] = v;
        }
}

// ---------------------------------------------------------------------------
// CONV2 (fine-grid 27-tap): block = 8 parents = 64 children, 256 threads.
// thread(tx -> 4 cols, ty -> parent ty's 8 children), acc[8] float4.
// Per tap d: each child's neighbor = 2*pc + obits + d; existence = parent
// occupancy; row = 8*grid32[nb>>1] + childbits(nb&1). Gather 64 rows to LDS,
// accumulate vs raw W2[d]. Per-row validity skip.
__global__ void __launch_bounds__(256) conv2_kernel(
    const float* __restrict__ h1, const float* __restrict__ W2,
    const float* __restrict__ b2, const int* __restrict__ grid32,
    const int* __restrict__ coords, const float* __restrict__ feats,
    float* __restrict__ out) {
    __shared__ int   pc[8][3];
    __shared__ int   rowsrc[64];
    __shared__ float inbuf[64 * 128];   // 32 KB
    int t = threadIdx.x;
    int P0 = blockIdx.x * 8;
    if (t < 24) pc[t / 3][t % 3] = coords[(P0 + t / 3) * 3 + t % 3];
    int tx = t & 31, ty = t >> 5;
    float4 acc[8];
#pragma unroll
    for (int r = 0; r < 8; ++r) acc[r] = make_float4(0.f, 0.f, 0.f, 0.f);
    __syncthreads();

#pragma unroll 1
    for (int k = 0; k < 27; ++k) {
        int dx = k / 9 - 1, dy = (k / 3) % 3 - 1, dz = k % 3 - 1;
        __syncthreads();   // previous compute done with inbuf/rowsrc
        if (t < 64) {
            int i = t >> 3, o = t & 7;
            int fx = 2 * pc[i][0] + ((o >> 2) & 1) + dx;
            int fy = 2 * pc[i][1] + ((o >> 1) & 1) + dy;
            int fz = 2 * pc[i][2] + (o & 1) + dz;
            int src = -1;
            if ((unsigned)fx < 64u && (unsigned)fy < 64u && (unsigned)fz < 64u) {
                int r = grid32[((fx >> 1) << 10) + ((fy >> 1) << 5) + (fz >> 1)];
                if (r >= 0) src = r * 8 + ((fx & 1) << 2) + ((fy & 1) << 1) + (fz & 1);
            }
            rowsrc[t] = src;
        }
        __syncthreads();
        // gather 64 rows; lane-contiguous LDS writes
#pragma unroll
        for (int j = 0; j < 8; ++j) {
            int row = j * 8 + ty;
            int src = rowsrc[row];
            float4 v = make_float4(0.f, 0.f, 0.f, 0.f);
            if (src >= 0) v = ((const float4*)h1)[src * 32 + tx];
            ((float4*)inbuf)[row * 32 + tx] = v;
        }
        __syncthreads();
        const float4* W4 = (const float4*)(W2 + k * 16384);
#pragma unroll
        for (int r = 0; r < 8; ++r) {
            if (rowsrc[ty * 8 + r] < 0) continue;
            const float4* A4 = (const float4*)(inbuf + (ty * 8 + r) * 128);
            float4 ac = acc[r];
#pragma unroll 4
            for (int ci4 = 0; ci4 < 32; ++ci4) {
                float4 a4 = A4[ci4];
                float4 w;
                w = W4[(ci4 * 4 + 0) * 32 + tx];
                ac.x = fmaf(a4.x, w.x, ac.x); ac.y = fmaf(a4.x, w.y, ac.y);
                ac.z = fmaf(a4.x, w.z, ac.z); ac.w = fmaf(a4.x, w.w, ac.w);
                w = W4[(ci4 * 4 + 1) * 32 + tx];
                ac.x = fmaf(a4.y, w.x, ac.x); ac.y = fmaf(a4.y, w.y, ac.y);
                ac.z = fmaf(a4.y, w.z, ac.z); ac.w = fmaf(a4.y, w.w, ac.w);
                w = W4[(ci4 * 4 + 2) * 32 + tx];
                ac.x = fmaf(a4.z, w.x, ac.x); ac.y = fmaf(a4.z, w.y, ac.y);
                ac.z = fmaf(a4.z, w.z, ac.z); ac.w = fmaf(a4.z, w.w, ac.w);
                w = W4[(ci4 * 4 + 3) * 32 + tx];
                ac.x = fmaf(a4.w, w.x, ac.x); ac.y = fmaf(a4.w, w.y, ac.y);
                ac.z = fmaf(a4.w, w.z, ac.z); ac.w = fmaf(a4.w, w.w, ac.w);
            }
            acc[r] = ac;
        }
    }
    float4 bias = ((const float4*)b2)[tx];
    float4 res  = ((const float4*)feats)[(P0 + ty) * 32 + tx];
#pragma unroll
    for (int r = 0; r < 8; ++r) {
        float4 v = acc[r];
        v.x += bias.x + res.x; v.y += bias.y + res.y;
        v.z += bias.z + res.z; v.w += bias.w + res.w;
        int R = (P0 + ty) * 8 + r;
        ((float4*)out)[R * 32 + tx] = v;
    }
}

// ---------------------------------------------------------------------------
extern "C" void kernel_launch(void* const* d_in, const int* in_sizes, int n_in,
                              void* d_out, int out_size, void* d_ws, size_t ws_size,
                              hipStream_t stream) {
    const float* feats  = (const float*)d_in[0];
    const float* gamma1 = (const float*)d_in[1];
    const float* beta1  = (const float*)d_in[2];
    const float* W1     = (const float*)d_in[3];
    const float* b1     = (const float*)d_in[4];
    const float* gamma2 = (const float*)d_in[5];
    const float* beta2  = (const float*)d_in[6];
    const float* W2     = (const float*)d_in[7];
    const float* b2     = (const float*)d_in[8];
    const int*   coords = (const int*)d_in[9];
    float* out = (float*)d_out;

    char* ws = (char*)d_ws;
    float* h0     = (float*)(ws);                                  // 4 MB
    float* h1     = (float*)(ws + (4u << 20));                     // 32 MB
    float* Wc1    = (float*)(ws + (36u << 20));                    // 4 MB
    int*   grid32 = (int*)  (ws + (40u << 20));                    // 128 KB
    float* stats  = (float*)(ws + (40u << 20) + (RES * RES * RES * 4));

    init_kernel<<<128, 256, 0, stream>>>(grid32, stats);
    scatter_kernel<<<NPAR / 256, 256, 0, stream>>>(coords, grid32);
    fold_kernel<<<(64 * 16384) / 256, 256, 0, stream>>>(W1, Wc1);

    gn_stats_kernel<<<256, 256, 0, stream>>>(feats, stats + 0, stats + 32, NPAR);
    gn_apply_kernel<<<256, 256, 0, stream>>>(feats, stats + 0, stats + 32, gamma1, beta1, h0, NPAR);

    conv1_kernel<<<NPAR / 16, 256, 0, stream>>>(h0, Wc1, b1, grid32, coords, h1);

    gn_stats_kernel<<<512, 256, 0, stream>>>(h1, stats + 64, stats + 96, NCH);
    gn_apply_kernel<<<512, 256, 0, stream>>>(h1, stats + 64, stats + 96, gamma2, beta2, h1, NCH);

    conv2_kernel<<<NPAR / 8, 256, 0, stream>>>(h1, W2, b2, grid32, coords, feats, out);
}

// Round 3
// 474.912 us; speedup vs baseline: 5.9921x; 5.9921x over previous
//
#include <hip/hip_runtime.h>

// Problem constants
#define NPAR   8192      // parents
#define NCH    65536     // children = NPAR*8
#define RES    32
#define EPS    1e-5f

typedef __attribute__((ext_vector_type(8))) short short8;
typedef __attribute__((ext_vector_type(4))) float floatx4;

__device__ __forceinline__ unsigned short f2bf(float f) {
    union { float f; unsigned u; } v; v.f = f;
    unsigned r = v.u + 0x7fffu + ((v.u >> 16) & 1u);   // RNE
    return (unsigned short)(r >> 16);
}

// ---------------------------------------------------------------------------
// init: grid32 = -1 (32768 = 128*256), stats[128] = 0
__global__ void init_kernel(int* __restrict__ grid32, float* __restrict__ stats) {
    int idx = blockIdx.x * 256 + threadIdx.x;
    grid32[idx] = -1;
    if (idx < 128) stats[idx] = 0.0f;
}

__global__ void scatter_kernel(const int* __restrict__ coords, int* __restrict__ grid32) {
    int p = blockIdx.x * 256 + threadIdx.x;
    if (p >= NPAR) return;
    grid32[(coords[p*3] << 10) + (coords[p*3+1] << 5) + coords[p*3+2]] = p;
}

// ---------------------------------------------------------------------------
// Weight prep: Wt[tap][n][k] = bf16(W[tap][k][n])  (transposed so MFMA B-frag
// reads are contiguous in LDS). 2 * 27 * 128 * 128 elements.
__global__ void wprep_kernel(const float* __restrict__ W1, const float* __restrict__ W2,
                             unsigned short* __restrict__ Wt1, unsigned short* __restrict__ Wt2) {
    int idx = blockIdx.x * 256 + threadIdx.x;      // < 884736
    int which = idx >= 442368 ? 1 : 0;
    int rem = idx - which * 442368;
    int tap = rem >> 14;
    int e   = rem & 16383;
    int n = e >> 7, k = e & 127;
    const float* W = which ? W2 : W1;
    unsigned short* Wt = which ? Wt2 : Wt1;
    Wt[rem] = f2bf(W[tap * 16384 + k * 128 + n]);
}

// ---------------------------------------------------------------------------
// GroupNorm stats over ALL rows (axis 0 and 2). C/G = 4 -> one float4 = one group.
__global__ void gn_stats_kernel(const float* __restrict__ x, float* __restrict__ sum,
                                float* __restrict__ sq, int nrows) {
    __shared__ float s_sum[32], s_sq[32];
    int t = threadIdx.x;
    if (t < 32) { s_sum[t] = 0.0f; s_sq[t] = 0.0f; }
    __syncthreads();
    const float4* x4 = (const float4*)x;
    int total = nrows * 32;
    int idx0 = blockIdx.x * blockDim.x + t;
    int g = idx0 & 31;
    float ls = 0.0f, lq = 0.0f;
    for (int idx = idx0; idx < total; idx += gridDim.x * blockDim.x) {
        float4 v = x4[idx];
        ls += v.x + v.y + v.z + v.w;
        lq += v.x * v.x + v.y * v.y + v.z * v.z + v.w * v.w;
    }
    atomicAdd(&s_sum[g], ls);
    atomicAdd(&s_sq[g], lq);
    __syncthreads();
    if (t < 32) { atomicAdd(&sum[t], s_sum[t]); atomicAdd(&sq[t], s_sq[t]); }
}

// groupnorm + silu, output bf16 (packed 4 ch = 8 B)
__global__ void gn_apply_kernel(const float* __restrict__ x, const float* __restrict__ sum,
                                const float* __restrict__ sq, const float* __restrict__ gamma,
                                const float* __restrict__ beta, unsigned short* __restrict__ y,
                                int nrows) {
    const float4* x4 = (const float4*)x;
    uint2* y2 = (uint2*)y;
    const float4* g4 = (const float4*)gamma;
    const float4* b4 = (const float4*)beta;
    float cnt = (float)nrows * 4.0f;
    int total = nrows * 32;
    for (int idx = blockIdx.x * blockDim.x + threadIdx.x; idx < total;
         idx += gridDim.x * blockDim.x) {
        int c4 = idx & 31;
        float mean = sum[c4] / cnt;
        float var = sq[c4] / cnt - mean * mean;
        float rstd = rsqrtf(var + EPS);
        float4 v = x4[idx];
        float4 gm = g4[c4];
        float4 bt = b4[c4];
        float a[4] = {v.x, v.y, v.z, v.w};
        float gg[4] = {gm.x, gm.y, gm.z, gm.w};
        float bb[4] = {bt.x, bt.y, bt.z, bt.w};
        unsigned short o[4];
#pragma unroll
        for (int i = 0; i < 4; ++i) {
            float tv = (a[i] - mean) * rstd * gg[i] + bb[i];
            o[i] = f2bf(tv / (1.0f + __expf(-tv)));
        }
        uint2 pk;
        pk.x = (unsigned)o[0] | ((unsigned)o[1] << 16);
        pk.y = (unsigned)o[2] | ((unsigned)o[3] << 16);
        y2[idx] = pk;
    }
}

// ---------------------------------------------------------------------------
// MFMA conv: block = 8 parents = 64 child rows, 256 threads = 4 waves.
// Per tap: gather 64 input rows (bf16) + stage W tap (bf16, [n][k]) into LDS,
// then dense GEMM C[64][128] += A @ W via 16x16x32 bf16 MFMA.
// child_mode 0 (conv1): input row = parent index (repeat(h,8) folded into gather)
// child_mode 1 (conv2): input row = parent*8 + child bits.
// Layouts (verified refs in guide): A-frag A[m=lane&15][k=quad*8+j];
// B-frag B[k=quad*8+j][n=lane&15] (reads from transposed W_lds[n][k]);
// C/D: col=lane&15, row=quad*4+reg.
__global__ void __launch_bounds__(256) conv_mfma_kernel(
    const unsigned short* __restrict__ Ag, const unsigned short* __restrict__ Wt,
    const float* __restrict__ bias, const int* __restrict__ grid32,
    const int* __restrict__ coords, const float* __restrict__ resid,
    float* __restrict__ out, int child_mode) {
    __shared__ unsigned short A_lds[64 * 136];    // 17408 B, stride 136 (pad 8)
    __shared__ unsigned short W_lds[128 * 136];   // 34816 B

    int t = threadIdx.x;
    int P0 = blockIdx.x * 8;

    // gather-role constants: 4 threads per row, row = t>>2, chunk = t&3
    int grow = t >> 2;             // 0..63
    int gch  = t & 3;              // 0..3 (32 bf16 each)
    int gi   = grow >> 3;          // parent in block
    int go   = grow & 7;           // child bits
    int px = coords[(P0 + gi) * 3 + 0];
    int py = coords[(P0 + gi) * 3 + 1];
    int pz = coords[(P0 + gi) * 3 + 2];
    int bx = 2 * px + ((go >> 2) & 1);
    int by = 2 * py + ((go >> 1) & 1);
    int bz = 2 * pz + (go & 1);

    // W-stage constants: thread copies 64 bf16: n = t>>1, half = t&1
    int wn = t >> 1, wh = t & 1;

    // MFMA constants
    int wv = t >> 6, lane = t & 63, quad = lane >> 4, l16 = lane & 15;

    floatx4 acc[4][2];
#pragma unroll
    for (int mt = 0; mt < 4; ++mt)
#pragma unroll
        for (int nt = 0; nt < 2; ++nt)
            acc[mt][nt] = (floatx4){0.f, 0.f, 0.f, 0.f};

#pragma unroll 1
    for (int k = 0; k < 27; ++k) {
        int dx = k / 9 - 1, dy = (k / 3) % 3 - 1, dz = k % 3 - 1;
        __syncthreads();   // previous tap's MFMA reads done

        // ---- gather A rows (redundant src calc across the 4 threads/row)
        {
            int fx = bx + dx, fy = by + dy, fz = bz + dz;
            long src = -1;
            if ((unsigned)fx < 64u && (unsigned)fy < 64u && (unsigned)fz < 64u) {
                int r = grid32[((fx >> 1) << 10) + ((fy >> 1) << 5) + (fz >> 1)];
                if (r >= 0)
                    src = child_mode ? (long)r * 8 + ((fx & 1) << 2) + ((fy & 1) << 1) + (fz & 1)
                                     : (long)r;
            }
            uint4* dst = (uint4*)&A_lds[grow * 136 + gch * 32];
            if (src >= 0) {
                const uint4* s4 = (const uint4*)(Ag + src * 128 + gch * 32);
#pragma unroll
                for (int i = 0; i < 4; ++i) dst[i] = s4[i];
            } else {
                uint4 z = {0u, 0u, 0u, 0u};
#pragma unroll
                for (int i = 0; i < 4; ++i) dst[i] = z;
            }
        }
        // ---- stage W tap (already [n][k] in global): 64 bf16 per thread
        {
            const uint4* s4 = (const uint4*)(Wt + k * 16384 + wn * 128 + wh * 64);
            uint4* dst = (uint4*)&W_lds[wn * 136 + wh * 64];
#pragma unroll
            for (int i = 0; i < 8; ++i) dst[i] = s4[i];
        }
        __syncthreads();

        // ---- dense GEMM on tile: wave wv owns cols [wv*32, wv*32+32)
        short8 bfr[2][4];
#pragma unroll
        for (int nt = 0; nt < 2; ++nt)
#pragma unroll
            for (int ks = 0; ks < 4; ++ks)
                bfr[nt][ks] = *(const short8*)&W_lds[(wv * 32 + nt * 16 + l16) * 136 + ks * 32 + quad * 8];
#pragma unroll
        for (int mt = 0; mt < 4; ++mt) {
            short8 afr[4];
#pragma unroll
            for (int ks = 0; ks < 4; ++ks)
                afr[ks] = *(const short8*)&A_lds[(mt * 16 + l16) * 136 + ks * 32 + quad * 8];
#pragma unroll
            for (int nt = 0; nt < 2; ++nt)
#pragma unroll
                for (int ks = 0; ks < 4; ++ks)
                    acc[mt][nt] = __builtin_amdgcn_mfma_f32_16x16x32_bf16(
                        afr[ks], bfr[nt][ks], acc[mt][nt], 0, 0, 0);
        }
    }

    // ---- epilogue: bias (+ residual) and store
#pragma unroll
    for (int nt = 0; nt < 2; ++nt) {
        int col = wv * 32 + nt * 16 + l16;
        float bv = bias[col];
#pragma unroll
        for (int mt = 0; mt < 4; ++mt) {
#pragma unroll
            for (int r = 0; r < 4; ++r) {
                int lrow = mt * 16 + quad * 4 + r;     // 0..63
                long R = (long)P0 * 8 + lrow;
                float v = acc[mt][nt][r] + bv;
                if (resid) v += resid[(R >> 3) * 128 + col];
                out[R * 128 + col] = v;
            }
        }
    }
}

// ---------------------------------------------------------------------------
extern "C" void kernel_launch(void* const* d_in, const int* in_sizes, int n_in,
                              void* d_out, int out_size, void* d_ws, size_t ws_size,
                              hipStream_t stream) {
    const float* feats  = (const float*)d_in[0];
    const float* gamma1 = (const float*)d_in[1];
    const float* beta1  = (const float*)d_in[2];
    const float* W1     = (const float*)d_in[3];
    const float* b1     = (const float*)d_in[4];
    const float* gamma2 = (const float*)d_in[5];
    const float* beta2  = (const float*)d_in[6];
    const float* W2     = (const float*)d_in[7];
    const float* b2     = (const float*)d_in[8];
    const int*   coords = (const int*)d_in[9];
    float* out = (float*)d_out;   // 65536 x 128 fp32; also used as h1 scratch

    char* ws = (char*)d_ws;
    unsigned short* h0b = (unsigned short*)(ws);                    // 2 MB  (8192x128 bf16)
    unsigned short* h1b = (unsigned short*)(ws + (2u << 20));       // 16 MB (65536x128 bf16)
    unsigned short* Wt1 = (unsigned short*)(ws + (18u << 20));      // 864 KB
    unsigned short* Wt2 = (unsigned short*)(ws + (19u << 20));      // 864 KB
    int*   grid32       = (int*)  (ws + (20u << 20));               // 128 KB
    float* stats        = (float*)(ws + (20u << 20) + (RES*RES*RES*4));

    init_kernel<<<128, 256, 0, stream>>>(grid32, stats);
    scatter_kernel<<<NPAR / 256, 256, 0, stream>>>(coords, grid32);
    wprep_kernel<<<884736 / 256, 256, 0, stream>>>(W1, W2, Wt1, Wt2);

    gn_stats_kernel<<<256, 256, 0, stream>>>(feats, stats + 0, stats + 32, NPAR);
    gn_apply_kernel<<<256, 256, 0, stream>>>(feats, stats + 0, stats + 32, gamma1, beta1, h0b, NPAR);

    // conv1: out (=h1 fp32) = conv(repeat(silu(gn(feats)),8))
    conv_mfma_kernel<<<NPAR / 8, 256, 0, stream>>>(h0b, Wt1, b1, grid32, coords,
                                                   nullptr, out, 0);

    gn_stats_kernel<<<512, 256, 0, stream>>>(out, stats + 64, stats + 96, NCH);
    gn_apply_kernel<<<512, 256, 0, stream>>>(out, stats + 64, stats + 96, gamma2, beta2, h1b, NCH);

    // conv2: out = conv(silu(gn(h1))) + repeat(feats,8)
    conv_mfma_kernel<<<NPAR / 8, 256, 0, stream>>>(h1b, Wt2, b2, grid32, coords,
                                                   feats, out, 1);
}

// Round 4
// 418.254 us; speedup vs baseline: 6.8038x; 1.1355x over previous
//
#include <hip/hip_runtime.h>

// Problem constants
#define NPAR   8192      // parents
#define NCH    65536     // children = NPAR*8
#define RES    32
#define EPS    1e-5f

typedef __attribute__((ext_vector_type(8))) short short8;
typedef __attribute__((ext_vector_type(4))) float floatx4;

__device__ __forceinline__ unsigned short f2bf(float f) {
    union { float f; unsigned u; } v; v.f = f;
    unsigned r = v.u + 0x7fffu + ((v.u >> 16) & 1u);   // RNE
    return (unsigned short)(r >> 16);
}

// ---------------------------------------------------------------------------
__global__ void init_kernel(int* __restrict__ grid32, float* __restrict__ stats) {
    int idx = blockIdx.x * 256 + threadIdx.x;
    grid32[idx] = -1;
    if (idx < 128) stats[idx] = 0.0f;
}

__global__ void scatter_kernel(const int* __restrict__ coords, int* __restrict__ grid32) {
    int p = blockIdx.x * 256 + threadIdx.x;
    if (p >= NPAR) return;
    grid32[(coords[p*3] << 10) + (coords[p*3+1] << 5) + coords[p*3+2]] = p;
}

// Neighbor-row index table: idx[k][R] = child-row index of neighbor of child R
// at tap k (or -1). conv2 uses it directly; conv1 (repeat-8 input) uses >>3.
__global__ void idx_kernel(const int* __restrict__ coords, const int* __restrict__ grid32,
                           int* __restrict__ idx_tab) {
    int R = blockIdx.x * 256 + threadIdx.x;   // 65536
    int p = R >> 3, o = R & 7;
    int bx = 2 * coords[p*3]   + ((o >> 2) & 1);
    int by = 2 * coords[p*3+1] + ((o >> 1) & 1);
    int bz = 2 * coords[p*3+2] + (o & 1);
#pragma unroll 1
    for (int k = 0; k < 27; ++k) {
        int fx = bx + k / 9 - 1, fy = by + (k / 3) % 3 - 1, fz = bz + k % 3 - 1;
        int src = -1;
        if ((unsigned)fx < 64u && (unsigned)fy < 64u && (unsigned)fz < 64u) {
            int r = grid32[((fx >> 1) << 10) + ((fy >> 1) << 5) + (fz >> 1)];
            if (r >= 0) src = r * 8 + ((fx & 1) << 2) + ((fy & 1) << 1) + (fz & 1);
        }
        idx_tab[k * NCH + R] = src;
    }
}

// ---------------------------------------------------------------------------
// Weight prep: Wt[tap][n][k] = bf16(W[tap][k][n])
__global__ void wprep_kernel(const float* __restrict__ W1, const float* __restrict__ W2,
                             unsigned short* __restrict__ Wt1, unsigned short* __restrict__ Wt2) {
    int idx = blockIdx.x * 256 + threadIdx.x;      // < 884736
    int which = idx >= 442368 ? 1 : 0;
    int rem = idx - which * 442368;
    int tap = rem >> 14;
    int e   = rem & 16383;
    int n = e >> 7, k = e & 127;
    const float* W = which ? W2 : W1;
    unsigned short* Wt = which ? Wt2 : Wt1;
    Wt[rem] = f2bf(W[tap * 16384 + k * 128 + n]);
}

// ---------------------------------------------------------------------------
__global__ void gn_stats_kernel(const float* __restrict__ x, float* __restrict__ sum,
                                float* __restrict__ sq, int nrows) {
    __shared__ float s_sum[32], s_sq[32];
    int t = threadIdx.x;
    if (t < 32) { s_sum[t] = 0.0f; s_sq[t] = 0.0f; }
    __syncthreads();
    const float4* x4 = (const float4*)x;
    int total = nrows * 32;
    int idx0 = blockIdx.x * blockDim.x + t;
    int g = idx0 & 31;
    float ls = 0.0f, lq = 0.0f;
    for (int idx = idx0; idx < total; idx += gridDim.x * blockDim.x) {
        float4 v = x4[idx];
        ls += v.x + v.y + v.z + v.w;
        lq += v.x * v.x + v.y * v.y + v.z * v.z + v.w * v.w;
    }
    atomicAdd(&s_sum[g], ls);
    atomicAdd(&s_sq[g], lq);
    __syncthreads();
    if (t < 32) { atomicAdd(&sum[t], s_sum[t]); atomicAdd(&sq[t], s_sq[t]); }
}

__global__ void gn_apply_kernel(const float* __restrict__ x, const float* __restrict__ sum,
                                const float* __restrict__ sq, const float* __restrict__ gamma,
                                const float* __restrict__ beta, unsigned short* __restrict__ y,
                                int nrows) {
    const float4* x4 = (const float4*)x;
    uint2* y2 = (uint2*)y;
    const float4* g4 = (const float4*)gamma;
    const float4* b4 = (const float4*)beta;
    float cnt = (float)nrows * 4.0f;
    int total = nrows * 32;
    for (int idx = blockIdx.x * blockDim.x + threadIdx.x; idx < total;
         idx += gridDim.x * blockDim.x) {
        int c4 = idx & 31;
        float mean = sum[c4] / cnt;
        float var = sq[c4] / cnt - mean * mean;
        float rstd = rsqrtf(var + EPS);
        float4 v = x4[idx];
        float4 gm = g4[c4];
        float4 bt = b4[c4];
        float a[4] = {v.x, v.y, v.z, v.w};
        float gg[4] = {gm.x, gm.y, gm.z, gm.w};
        float bb[4] = {bt.x, bt.y, bt.z, bt.w};
        unsigned short o[4];
#pragma unroll
        for (int i = 0; i < 4; ++i) {
            float tv = (a[i] - mean) * rstd * gg[i] + bb[i];
            o[i] = f2bf(tv / (1.0f + __expf(-tv)));
        }
        uint2 pk;
        pk.x = (unsigned)o[0] | ((unsigned)o[1] << 16);
        pk.y = (unsigned)o[2] | ((unsigned)o[3] << 16);
        y2[idx] = pk;
    }
}

// ---------------------------------------------------------------------------
// Pipelined MFMA conv: block = 64 child rows (8 parents), 256 threads = 4 waves.
// A double-buffered in LDS (2 x 17408 B); B-frags read directly from global Wt
// (tap-identical across blocks -> L1/L2-hot); A rows for tap k+1 prefetched
// into registers during tap k's MFMAs; idx loaded two taps ahead.
// shift=3: conv1 (input row = idx>>3, repeat-8 folded); shift=0: conv2.
// gsum/gsq non-null: fuse next groupnorm's stats reduction into the epilogue.
__global__ void __launch_bounds__(256) conv_mfma_kernel(
    const unsigned short* __restrict__ Ag, const unsigned short* __restrict__ Wt,
    const float* __restrict__ bias, const int* __restrict__ idx_tab,
    const float* __restrict__ resid, float* __restrict__ out,
    int shift, float* __restrict__ gsum, float* __restrict__ gsq) {
    __shared__ unsigned short A_lds[2][64 * 136];  // stride 136: even bank spread
    __shared__ float sred[64];

    int t = threadIdx.x;
    int R0 = blockIdx.x * 64;
    int grow = t >> 2;             // row 0..63 (4 threads per row)
    int gch  = t & 3;              // 64 B chunk within row
    int wv = t >> 6, lane = t & 63, quad = lane >> 4, l16 = lane & 15;

    floatx4 acc[4][2];
#pragma unroll
    for (int mt = 0; mt < 4; ++mt)
#pragma unroll
        for (int nt = 0; nt < 2; ++nt)
            acc[mt][nt] = (floatx4){0.f, 0.f, 0.f, 0.f};

    uint4 apf[4];
    // ---- prolog: tap 0 into LDS buf 0, idx for tap 1 in flight
    int idxv = idx_tab[R0 + grow];
    {
        long src = (long)(idxv >> shift);
        if (idxv >= 0) {
            const uint4* s4 = (const uint4*)(Ag + src * 128 + gch * 32);
#pragma unroll
            for (int i = 0; i < 4; ++i) apf[i] = s4[i];
        } else {
            uint4 z = {0u, 0u, 0u, 0u};
#pragma unroll
            for (int i = 0; i < 4; ++i) apf[i] = z;
        }
    }
    int idx_nxt = idx_tab[NCH + R0 + grow];
    {
        uint4* dst = (uint4*)&A_lds[0][grow * 136 + gch * 32];
#pragma unroll
        for (int i = 0; i < 4; ++i) dst[i] = apf[i];
    }
    __syncthreads();

#pragma unroll 1
    for (int k = 0; k < 27; ++k) {
        int cur = k & 1;
        // ---- B fragments for tap k (global; same bytes for every block)
        const unsigned short* Wk = Wt + k * 16384;
        short8 bfr[2][4];
#pragma unroll
        for (int nt = 0; nt < 2; ++nt)
#pragma unroll
            for (int ks = 0; ks < 4; ++ks)
                bfr[nt][ks] = *(const short8*)&Wk[(wv * 32 + nt * 16 + l16) * 128 + ks * 32 + quad * 8];
        // ---- prefetch A rows for tap k+1 into registers
        if (k < 26) {
            long src = (long)(idx_nxt >> shift);
            if (idx_nxt >= 0) {
                const uint4* s4 = (const uint4*)(Ag + src * 128 + gch * 32);
#pragma unroll
                for (int i = 0; i < 4; ++i) apf[i] = s4[i];
            } else {
                uint4 z = {0u, 0u, 0u, 0u};
#pragma unroll
                for (int i = 0; i < 4; ++i) apf[i] = z;
            }
            if (k < 25) idx_nxt = idx_tab[(k + 2) * NCH + R0 + grow];
        }
        // ---- MFMA on tap k from LDS[cur] + bfr
#pragma unroll
        for (int mt = 0; mt < 4; ++mt) {
            short8 afr[4];
#pragma unroll
            for (int ks = 0; ks < 4; ++ks)
                afr[ks] = *(const short8*)&A_lds[cur][(mt * 16 + l16) * 136 + ks * 32 + quad * 8];
#pragma unroll
            for (int nt = 0; nt < 2; ++nt)
#pragma unroll
                for (int ks = 0; ks < 4; ++ks)
                    acc[mt][nt] = __builtin_amdgcn_mfma_f32_16x16x32_bf16(
                        afr[ks], bfr[nt][ks], acc[mt][nt], 0, 0, 0);
        }
        // ---- commit prefetched rows to the other buffer
        if (k < 26) {
            uint4* dst = (uint4*)&A_lds[1 - cur][grow * 136 + gch * 32];
#pragma unroll
            for (int i = 0; i < 4; ++i) dst[i] = apf[i];
        }
        __syncthreads();
    }

    // ---- epilogue: bias (+residual) store; optional fused GN stats
    float s[2] = {0.f, 0.f}, q[2] = {0.f, 0.f};
#pragma unroll
    for (int nt = 0; nt < 2; ++nt) {
        int col = wv * 32 + nt * 16 + l16;
        float bv = bias[col];
#pragma unroll
        for (int mt = 0; mt < 4; ++mt) {
#pragma unroll
            for (int r = 0; r < 4; ++r) {
                int row = mt * 16 + quad * 4 + r;
                long R = (long)R0 + row;
                float v = acc[mt][nt][r] + bv;
                if (resid) v += resid[(R >> 3) * 128 + col];
                out[R * 128 + col] = v;
                s[nt] += v;
                q[nt] += v * v;
            }
        }
    }
    if (gsum) {
        if (t < 64) sred[t] = 0.0f;
        __syncthreads();
#pragma unroll
        for (int nt = 0; nt < 2; ++nt) {
            int g = (wv * 32 + nt * 16 + l16) >> 2;
            atomicAdd(&sred[g], s[nt]);
            atomicAdd(&sred[32 + g], q[nt]);
        }
        __syncthreads();
        if (t < 32) { atomicAdd(&gsum[t], sred[t]); atomicAdd(&gsq[t], sred[32 + t]); }
    }
}

// ---------------------------------------------------------------------------
extern "C" void kernel_launch(void* const* d_in, const int* in_sizes, int n_in,
                              void* d_out, int out_size, void* d_ws, size_t ws_size,
                              hipStream_t stream) {
    const float* feats  = (const float*)d_in[0];
    const float* gamma1 = (const float*)d_in[1];
    const float* beta1  = (const float*)d_in[2];
    const float* W1     = (const float*)d_in[3];
    const float* b1     = (const float*)d_in[4];
    const float* gamma2 = (const float*)d_in[5];
    const float* beta2  = (const float*)d_in[6];
    const float* W2     = (const float*)d_in[7];
    const float* b2     = (const float*)d_in[8];
    const int*   coords = (const int*)d_in[9];
    float* out = (float*)d_out;   // 65536 x 128 fp32; also h1 scratch

    char* ws = (char*)d_ws;
    unsigned short* h0b = (unsigned short*)(ws);                    // 2 MB
    unsigned short* h1b = (unsigned short*)(ws + (2u << 20));       // 16 MB
    unsigned short* Wt1 = (unsigned short*)(ws + (18u << 20));      // 864 KB
    unsigned short* Wt2 = (unsigned short*)(ws + (19u << 20));      // 864 KB
    int*   grid32       = (int*)  (ws + (20u << 20));               // 128 KB
    float* stats        = (float*)(ws + (20u << 20) + (RES*RES*RES*4));
    int*   idx_tab      = (int*)  (ws + (21u << 20));               // 7.08 MB

    init_kernel<<<128, 256, 0, stream>>>(grid32, stats);
    scatter_kernel<<<NPAR / 256, 256, 0, stream>>>(coords, grid32);
    wprep_kernel<<<884736 / 256, 256, 0, stream>>>(W1, W2, Wt1, Wt2);
    idx_kernel<<<NCH / 256, 256, 0, stream>>>(coords, grid32, idx_tab);

    gn_stats_kernel<<<256, 256, 0, stream>>>(feats, stats + 0, stats + 32, NPAR);
    gn_apply_kernel<<<256, 256, 0, stream>>>(feats, stats + 0, stats + 32, gamma1, beta1, h0b, NPAR);

    // conv1 (+fused GN2 stats): out = conv(repeat(silu(gn1(feats)),8))
    conv_mfma_kernel<<<NCH / 64, 256, 0, stream>>>(h0b, Wt1, b1, idx_tab,
                                                   nullptr, out, 3, stats + 64, stats + 96);

    gn_apply_kernel<<<512, 256, 0, stream>>>(out, stats + 64, stats + 96, gamma2, beta2, h1b, NCH);

    // conv2: out = conv(silu(gn2(h1))) + repeat(feats,8)
    conv_mfma_kernel<<<NCH / 64, 256, 0, stream>>>(h1b, Wt2, b2, idx_tab,
                                                   feats, out, 0, nullptr, nullptr);
}

// Round 5
// 285.021 us; speedup vs baseline: 9.9843x; 1.4674x over previous
//
#include <hip/hip_runtime.h>

// Problem constants
#define NPAR   8192      // parents
#define NCH    65536     // children = NPAR*8
#define RES    32
#define EPS    1e-5f

typedef __attribute__((ext_vector_type(8))) short short8;
typedef __attribute__((ext_vector_type(4))) float floatx4;

__device__ __forceinline__ unsigned short f2bf(float f) {
    union { float f; unsigned u; } v; v.f = f;
    unsigned r = v.u + 0x7fffu + ((v.u >> 16) & 1u);   // RNE
    return (unsigned short)(r >> 16);
}

// ---------------------------------------------------------------------------
__global__ void init_kernel(int* __restrict__ grid32, float* __restrict__ stats) {
    int idx = blockIdx.x * 256 + threadIdx.x;
    grid32[idx] = -1;
    if (idx < 128) stats[idx] = 0.0f;
}

__global__ void scatter_kernel(const int* __restrict__ coords, int* __restrict__ grid32) {
    int p = blockIdx.x * 256 + threadIdx.x;
    if (p >= NPAR) return;
    grid32[(coords[p*3] << 10) + (coords[p*3+1] << 5) + coords[p*3+2]] = p;
}

// Neighbor-row index table: idx[k][R] = child-row index of neighbor of child R
// at tap k (or -1). conv2 uses it directly; conv1 (repeat-8 input) uses >>3.
__global__ void idx_kernel(const int* __restrict__ coords, const int* __restrict__ grid32,
                           int* __restrict__ idx_tab) {
    int R = blockIdx.x * 256 + threadIdx.x;   // 65536
    int p = R >> 3, o = R & 7;
    int bx = 2 * coords[p*3]   + ((o >> 2) & 1);
    int by = 2 * coords[p*3+1] + ((o >> 1) & 1);
    int bz = 2 * coords[p*3+2] + (o & 1);
#pragma unroll 1
    for (int k = 0; k < 27; ++k) {
        int fx = bx + k / 9 - 1, fy = by + (k / 3) % 3 - 1, fz = bz + k % 3 - 1;
        int src = -1;
        if ((unsigned)fx < 64u && (unsigned)fy < 64u && (unsigned)fz < 64u) {
            int r = grid32[((fx >> 1) << 10) + ((fy >> 1) << 5) + (fz >> 1)];
            if (r >= 0) src = r * 8 + ((fx & 1) << 2) + ((fy & 1) << 1) + (fz & 1);
        }
        idx_tab[k * NCH + R] = src;
    }
}

// ---------------------------------------------------------------------------
// Weight prep in FRAGMENT ORDER: Wp[tap][nb][ks][lane][j], j=0..7 bf16.
// lane = quad*16 + l16; element = W[tap][ks*32+quad*8+j][nb*16+l16].
// A wave's B-frag load is then lane*16B -> perfectly coalesced 1KB.
__global__ void wprep_kernel(const float* __restrict__ W1, const float* __restrict__ W2,
                             unsigned short* __restrict__ Wp1, unsigned short* __restrict__ Wp2) {
    int idx = blockIdx.x * 256 + threadIdx.x;      // 2 * 55296
    int which = idx >= 55296 ? 1 : 0;
    int rem = idx - which * 55296;
    int lane = rem & 63;
    int ks   = (rem >> 6) & 3;
    int nb   = (rem >> 8) & 7;
    int tap  = rem >> 11;                           // 0..26
    int n  = nb * 16 + (lane & 15);
    int k0 = ks * 32 + (lane >> 4) * 8;
    const float* W = which ? W2 : W1;
    unsigned short* Wp = which ? Wp2 : Wp1;
    unsigned short v[8];
#pragma unroll
    for (int j = 0; j < 8; ++j) v[j] = f2bf(W[tap * 16384 + (k0 + j) * 128 + n]);
    uint4 pk;
    pk.x = (unsigned)v[0] | ((unsigned)v[1] << 16);
    pk.y = (unsigned)v[2] | ((unsigned)v[3] << 16);
    pk.z = (unsigned)v[4] | ((unsigned)v[5] << 16);
    pk.w = (unsigned)v[6] | ((unsigned)v[7] << 16);
    *(uint4*)&Wp[(long)rem * 8] = pk;
}

// ---------------------------------------------------------------------------
__global__ void gn_stats_kernel(const float* __restrict__ x, float* __restrict__ sum,
                                float* __restrict__ sq, int nrows) {
    __shared__ float s_sum[32], s_sq[32];
    int t = threadIdx.x;
    if (t < 32) { s_sum[t] = 0.0f; s_sq[t] = 0.0f; }
    __syncthreads();
    const float4* x4 = (const float4*)x;
    int total = nrows * 32;
    int idx0 = blockIdx.x * blockDim.x + t;
    int g = idx0 & 31;
    float ls = 0.0f, lq = 0.0f;
    for (int idx = idx0; idx < total; idx += gridDim.x * blockDim.x) {
        float4 v = x4[idx];
        ls += v.x + v.y + v.z + v.w;
        lq += v.x * v.x + v.y * v.y + v.z * v.z + v.w * v.w;
    }
    atomicAdd(&s_sum[g], ls);
    atomicAdd(&s_sq[g], lq);
    __syncthreads();
    if (t < 32) { atomicAdd(&sum[t], s_sum[t]); atomicAdd(&sq[t], s_sq[t]); }
}

__global__ void gn_apply_kernel(const float* __restrict__ x, const float* __restrict__ sum,
                                const float* __restrict__ sq, const float* __restrict__ gamma,
                                const float* __restrict__ beta, unsigned short* __restrict__ y,
                                int nrows) {
    const float4* x4 = (const float4*)x;
    uint2* y2 = (uint2*)y;
    const float4* g4 = (const float4*)gamma;
    const float4* b4 = (const float4*)beta;
    float cnt = (float)nrows * 4.0f;
    int total = nrows * 32;
    for (int idx = blockIdx.x * blockDim.x + threadIdx.x; idx < total;
         idx += gridDim.x * blockDim.x) {
        int c4 = idx & 31;
        float mean = sum[c4] / cnt;
        float var = sq[c4] / cnt - mean * mean;
        float rstd = rsqrtf(var + EPS);
        float4 v = x4[idx];
        float4 gm = g4[c4];
        float4 bt = b4[c4];
        float a[4] = {v.x, v.y, v.z, v.w};
        float gg[4] = {gm.x, gm.y, gm.z, gm.w};
        float bb[4] = {bt.x, bt.y, bt.z, bt.w};
        unsigned short o[4];
#pragma unroll
        for (int i = 0; i < 4; ++i) {
            float tv = (a[i] - mean) * rstd * gg[i] + bb[i];
            o[i] = f2bf(tv / (1.0f + __expf(-tv)));
        }
        uint2 pk;
        pk.x = (unsigned)o[0] | ((unsigned)o[1] << 16);
        pk.y = (unsigned)o[2] | ((unsigned)o[3] << 16);
        y2[idx] = pk;
    }
}

// ---------------------------------------------------------------------------
// Pipelined MFMA conv. A in LDS, fragment-order with XOR swizzle:
//   slot(ks,row,q') at short-offset ks*2048 + row*32 + q'*8, q' = quad^((row>>1)&3)
// -> both the 16 ds_read_b128/tap and 4 ds_write_b128/tap are bank-conflict-free
//    (each instr covers every bank exactly 8x = b128 minimum).
// B-frags direct from packed global Wp (coalesced 1KB/instr, L1-hot).
__global__ void __launch_bounds__(256) conv_mfma_kernel(
    const unsigned short* __restrict__ Ag, const unsigned short* __restrict__ Wp,
    const float* __restrict__ bias, const int* __restrict__ idx_tab,
    const float* __restrict__ resid, float* __restrict__ out,
    int shift, float* __restrict__ gsum, float* __restrict__ gsq) {
    __shared__ unsigned short A_lds[2][8192];   // 2 x 16384 B
    __shared__ float sred[64];

    int t = threadIdx.x;
    int R0 = blockIdx.x * 64;
    int grow = t >> 2;             // row 0..63 (4 threads per row)
    int gch  = t & 3;              // k-slice (64 B chunk)
    int gsw  = (grow >> 1) & 3;    // write swizzle
    int wv = t >> 6, lane = t & 63, quad = lane >> 4, l16 = lane & 15;
    int rsw = (l16 >> 1) & 3;      // read swizzle

    floatx4 acc[4][2];
#pragma unroll
    for (int mt = 0; mt < 4; ++mt)
#pragma unroll
        for (int nt = 0; nt < 2; ++nt)
            acc[mt][nt] = (floatx4){0.f, 0.f, 0.f, 0.f};

    uint4 apf[4];
    // ---- prolog: tap 0 into LDS buf 0
    int idxv = idx_tab[R0 + grow];
    {
        long src = (long)(idxv >> shift);
        if (idxv >= 0) {
            const uint4* s4 = (const uint4*)(Ag + src * 128 + gch * 32);
#pragma unroll
            for (int i = 0; i < 4; ++i) apf[i] = s4[i];
        } else {
            uint4 z = {0u, 0u, 0u, 0u};
#pragma unroll
            for (int i = 0; i < 4; ++i) apf[i] = z;
        }
    }
    int idx_nxt = idx_tab[NCH + R0 + grow];
#pragma unroll
    for (int i = 0; i < 4; ++i)
        *(uint4*)&A_lds[0][gch * 2048 + grow * 32 + ((i ^ gsw) << 3)] = apf[i];
    __syncthreads();

#pragma unroll 1
    for (int k = 0; k < 27; ++k) {
        int cur = k & 1;
        // ---- B fragments for tap k (packed global; coalesced; block-shared bytes)
        short8 bfr[2][4];
#pragma unroll
        for (int nt = 0; nt < 2; ++nt)
#pragma unroll
            for (int ks = 0; ks < 4; ++ks)
                bfr[nt][ks] = *(const short8*)&Wp[((((k << 3) + (wv << 1) + nt) << 2) + ks) * 512 + (lane << 3)];
        // ---- prefetch A rows for tap k+1 into registers
        if (k < 26) {
            long src = (long)(idx_nxt >> shift);
            if (idx_nxt >= 0) {
                const uint4* s4 = (const uint4*)(Ag + src * 128 + gch * 32);
#pragma unroll
                for (int i = 0; i < 4; ++i) apf[i] = s4[i];
            } else {
                uint4 z = {0u, 0u, 0u, 0u};
#pragma unroll
                for (int i = 0; i < 4; ++i) apf[i] = z;
            }
            if (k < 25) idx_nxt = idx_tab[(k + 2) * NCH + R0 + grow];
        }
        // ---- MFMA on tap k from LDS[cur] + bfr
#pragma unroll
        for (int mt = 0; mt < 4; ++mt) {
            short8 afr[4];
#pragma unroll
            for (int ks = 0; ks < 4; ++ks)
                afr[ks] = *(const short8*)&A_lds[cur][ks * 2048 + (mt * 16 + l16) * 32 + ((quad ^ rsw) << 3)];
#pragma unroll
            for (int nt = 0; nt < 2; ++nt)
#pragma unroll
                for (int ks = 0; ks < 4; ++ks)
                    acc[mt][nt] = __builtin_amdgcn_mfma_f32_16x16x32_bf16(
                        afr[ks], bfr[nt][ks], acc[mt][nt], 0, 0, 0);
        }
        // ---- commit prefetched rows to the other buffer
        if (k < 26) {
#pragma unroll
            for (int i = 0; i < 4; ++i)
                *(uint4*)&A_lds[1 - cur][gch * 2048 + grow * 32 + ((i ^ gsw) << 3)] = apf[i];
        }
        __syncthreads();
    }

    // ---- epilogue: bias (+residual) store; optional fused GN stats
    float s[2] = {0.f, 0.f}, q[2] = {0.f, 0.f};
#pragma unroll
    for (int nt = 0; nt < 2; ++nt) {
        int col = wv * 32 + nt * 16 + l16;
        float bv = bias[col];
#pragma unroll
        for (int mt = 0; mt < 4; ++mt) {
#pragma unroll
            for (int r = 0; r < 4; ++r) {
                int row = mt * 16 + quad * 4 + r;
                long R = (long)R0 + row;
                float v = acc[mt][nt][r] + bv;
                if (resid) v += resid[(R >> 3) * 128 + col];
                out[R * 128 + col] = v;
                s[nt] += v;
                q[nt] += v * v;
            }
        }
    }
    if (gsum) {
        if (t < 64) sred[t] = 0.0f;
        __syncthreads();
#pragma unroll
        for (int nt = 0; nt < 2; ++nt) {
            int g = (wv * 32 + nt * 16 + l16) >> 2;
            atomicAdd(&sred[g], s[nt]);
            atomicAdd(&sred[32 + g], q[nt]);
        }
        __syncthreads();
        if (t < 32) { atomicAdd(&gsum[t], sred[t]); atomicAdd(&gsq[t], sred[32 + t]); }
    }
}

// ---------------------------------------------------------------------------
extern "C" void kernel_launch(void* const* d_in, const int* in_sizes, int n_in,
                              void* d_out, int out_size, void* d_ws, size_t ws_size,
                              hipStream_t stream) {
    const float* feats  = (const float*)d_in[0];
    const float* gamma1 = (const float*)d_in[1];
    const float* beta1  = (const float*)d_in[2];
    const float* W1     = (const float*)d_in[3];
    const float* b1     = (const float*)d_in[4];
    const float* gamma2 = (const float*)d_in[5];
    const float* beta2  = (const float*)d_in[6];
    const float* W2     = (const float*)d_in[7];
    const float* b2     = (const float*)d_in[8];
    const int*   coords = (const int*)d_in[9];
    float* out = (float*)d_out;   // 65536 x 128 fp32; also h1 scratch

    char* ws = (char*)d_ws;
    unsigned short* h0b = (unsigned short*)(ws);                    // 2 MB
    unsigned short* h1b = (unsigned short*)(ws + (2u << 20));       // 16 MB
    unsigned short* Wp1 = (unsigned short*)(ws + (18u << 20));      // 864 KB
    unsigned short* Wp2 = (unsigned short*)(ws + (19u << 20));      // 864 KB
    int*   grid32       = (int*)  (ws + (20u << 20));               // 128 KB
    float* stats        = (float*)(ws + (20u << 20) + (RES*RES*RES*4));
    int*   idx_tab      = (int*)  (ws + (21u << 20));               // 7.08 MB

    init_kernel<<<128, 256, 0, stream>>>(grid32, stats);
    scatter_kernel<<<NPAR / 256, 256, 0, stream>>>(coords, grid32);
    wprep_kernel<<<(2 * 55296) / 256, 256, 0, stream>>>(W1, W2, Wp1, Wp2);
    idx_kernel<<<NCH / 256, 256, 0, stream>>>(coords, grid32, idx_tab);

    gn_stats_kernel<<<256, 256, 0, stream>>>(feats, stats + 0, stats + 32, NPAR);
    gn_apply_kernel<<<256, 256, 0, stream>>>(feats, stats + 0, stats + 32, gamma1, beta1, h0b, NPAR);

    // conv1 (+fused GN2 stats): out = conv(repeat(silu(gn1(feats)),8))
    conv_mfma_kernel<<<NCH / 64, 256, 0, stream>>>(h0b, Wp1, b1, idx_tab,
                                                   nullptr, out, 3, stats + 64, stats + 96);

    gn_apply_kernel<<<512, 256, 0, stream>>>(out, stats + 64, stats + 96, gamma2, beta2, h1b, NCH);

    // conv2: out = conv(silu(gn2(h1))) + repeat(feats,8)
    conv_mfma_kernel<<<NCH / 64, 256, 0, stream>>>(h1b, Wp2, b2, idx_tab,
                                                   feats, out, 0, nullptr, nullptr);
}